// Round 3
// baseline (228.449 us; speedup 1.0000x reference)
//
#include <hip/hip_runtime.h>
#include <hip/hip_bf16.h>
#include <stdint.h>

// MultiHeadAttention fused forward, MI355X/gfx950.
// B=4, S=2048, H=16, hd=64, D=1024. fp32 in/out, bf16 MFMA internally.

typedef __attribute__((ext_vector_type(8))) __bf16 bf16x8;
typedef __attribute__((ext_vector_type(4))) float f32x4;
typedef __attribute__((ext_vector_type(16))) float f32x16;

#define AS_G __attribute__((address_space(1)))
#define AS_L __attribute__((address_space(3)))

__device__ __forceinline__ void gload_lds16(const void* g, void* s) {
  __builtin_amdgcn_global_load_lds((const AS_G void*)g, (AS_L void*)s, 16, 0, 0);
}

__device__ __forceinline__ unsigned cvt_pk_bf16(float lo, float hi) {
  unsigned r;
  asm("v_cvt_pk_bf16_f32 %0, %1, %2" : "=v"(r) : "v"(lo), "v"(hi));
  return r;
}

// ---------------------------------------------------------------- converts
__global__ void cvt_bf16_kernel(const float* __restrict__ in,
                                __bf16* __restrict__ out, int n8) {
  int i = blockIdx.x * blockDim.x + threadIdx.x;
  if (i >= n8) return;
  float4 a = ((const float4*)in)[i * 2];
  float4 b = ((const float4*)in)[i * 2 + 1];
  union { __bf16 h[8]; int4 v; } u;
  u.h[0] = (__bf16)a.x; u.h[1] = (__bf16)a.y; u.h[2] = (__bf16)a.z; u.h[3] = (__bf16)a.w;
  u.h[4] = (__bf16)b.x; u.h[5] = (__bf16)b.y; u.h[6] = (__bf16)b.z; u.h[7] = (__bf16)b.w;
  ((int4*)out)[i] = u.v;
}

// out[n*K + k] = (bf16) in[k*N + n]
__global__ void cvt_T_kernel(const float* __restrict__ in,
                             __bf16* __restrict__ out, int K, int N) {
  __shared__ float tile[32][33];
  int bx = blockIdx.x;  // along N
  int by = blockIdx.y;  // along K
  int tx = threadIdx.x & 31, ty = threadIdx.x >> 5;  // 32 x 8
#pragma unroll
  for (int i = 0; i < 32; i += 8)
    tile[ty + i][tx] = in[(size_t)(by * 32 + ty + i) * N + bx * 32 + tx];
  __syncthreads();
#pragma unroll
  for (int i = 0; i < 32; i += 8)
    out[(size_t)(bx * 32 + ty + i) * K + by * 32 + tx] = (__bf16)tile[tx][ty + i];
}

// ---------------------------------------------------------------- GEMM
// C[M,1024-chunked-N] = A[M,1024] @ Bt[N,1024]^T   (K = 1024 for both GEMMs)
// MODE 0: QKV projection epilogue (scatter Q*(log2e/8) / K / V-transposed, +bias)
// MODE 1: output projection epilogue (fp32 out, +bias)
template <int MODE>
__global__ __launch_bounds__(256) void gemm_bt(
    const __bf16* __restrict__ A, const __bf16* __restrict__ Bt,
    const float* __restrict__ bias,
    __bf16* __restrict__ Qb, __bf16* __restrict__ Kb, __bf16* __restrict__ Vtb,
    float* __restrict__ Out) {
  __shared__ __bf16 As[128 * 32];
  __shared__ __bf16 Bs[128 * 32];
  const int tid = threadIdx.x;
  const int wave = tid >> 6, lane = tid & 63;
  const int lhi = lane >> 4, llo = lane & 15;
  const int wm = wave >> 1, wn = wave & 1;
  const int m0 = blockIdx.y * 128, n0 = blockIdx.x * 128;

  const int srow = lane >> 2;         // 0..15 within a 16-row issue
  const int scol = (lane & 3) * 8;    // element column (x8 bf16 = 16B)
  const __bf16* Ag0 = A + (size_t)(m0 + (wave * 2 + 0) * 16 + srow) * 1024 + scol;
  const __bf16* Ag1 = A + (size_t)(m0 + (wave * 2 + 1) * 16 + srow) * 1024 + scol;
  const __bf16* Bg0 = Bt + (size_t)(n0 + (wave * 2 + 0) * 16 + srow) * 1024 + scol;
  const __bf16* Bg1 = Bt + (size_t)(n0 + (wave * 2 + 1) * 16 + srow) * 1024 + scol;
  __bf16* As0 = As + (wave * 2 + 0) * 512;
  __bf16* As1 = As + (wave * 2 + 1) * 512;
  __bf16* Bs0 = Bs + (wave * 2 + 0) * 512;
  __bf16* Bs1 = Bs + (wave * 2 + 1) * 512;

  f32x4 acc[4][4];
#pragma unroll
  for (int m = 0; m < 4; ++m)
#pragma unroll
    for (int n = 0; n < 4; ++n) acc[m][n] = (f32x4){0.f, 0.f, 0.f, 0.f};

  for (int k0 = 0; k0 < 1024; k0 += 32) {
    gload_lds16(Ag0 + k0, As0);
    gload_lds16(Ag1 + k0, As1);
    gload_lds16(Bg0 + k0, Bs0);
    gload_lds16(Bg1 + k0, Bs1);
    __syncthreads();
    bf16x8 af[4], bfr[4];
#pragma unroll
    for (int i = 0; i < 4; ++i)
      af[i] = *(const bf16x8*)&As[(wm * 64 + i * 16 + llo) * 32 + lhi * 8];
#pragma unroll
    for (int i = 0; i < 4; ++i)
      bfr[i] = *(const bf16x8*)&Bs[(wn * 64 + i * 16 + llo) * 32 + lhi * 8];
#pragma unroll
    for (int m = 0; m < 4; ++m)
#pragma unroll
      for (int n = 0; n < 4; ++n)
        acc[m][n] = __builtin_amdgcn_mfma_f32_16x16x32_bf16(af[m], bfr[n],
                                                            acc[m][n], 0, 0, 0);
    __syncthreads();
  }

#pragma unroll
  for (int ni = 0; ni < 4; ++ni) {
    const int col = n0 + wn * 64 + ni * 16 + llo;
    const float bv = bias[col];
    if (MODE == 0) {
      const int h = col / 192, rem = col % 192;
#pragma unroll
      for (int mi = 0; mi < 4; ++mi) {
        const int row0 = m0 + wm * 64 + mi * 16 + lhi * 4;
        const int b = row0 >> 11;
        const int s0 = row0 & 2047;
        const int bh = b * 16 + h;
        f32x4 v = acc[mi][ni];
        if (rem < 64) {
          // Q pre-scaled by (1/sqrt(64)) * log2(e) for exp2-domain softmax
#pragma unroll
          for (int r = 0; r < 4; ++r)
            Qb[((size_t)bh * 2048 + s0 + r) * 64 + rem] =
                (__bf16)((v[r] + bv) * 0.18033688011112042f);
        } else if (rem < 128) {
#pragma unroll
          for (int r = 0; r < 4; ++r)
            Kb[((size_t)bh * 2048 + s0 + r) * 64 + (rem - 64)] = (__bf16)(v[r] + bv);
        } else {
          union { __bf16 h4[4]; int2 v2; } u;
#pragma unroll
          for (int r = 0; r < 4; ++r) u.h4[r] = (__bf16)(v[r] + bv);
          *(int2*)&Vtb[((size_t)bh * 64 + (rem - 128)) * 2048 + s0] = u.v2;
        }
      }
    } else {
#pragma unroll
      for (int mi = 0; mi < 4; ++mi) {
        const int row0 = m0 + wm * 64 + mi * 16 + lhi * 4;
        f32x4 v = acc[mi][ni];
#pragma unroll
        for (int r = 0; r < 4; ++r)
          Out[(size_t)(row0 + r) * 1024 + col] = v[r] + bv;
      }
    }
  }
}

// ---------------------------------------------------------------- attention
// 4 waves x 32 q-rows; each block owns chunk pair (j, 15-j) of 128 rows each
// (perfect causal load balance: every block = 34 tile-units), staging each
// 64-KV tile ONCE and computing both chunks on it.
// Swapped QK^T: S^T = mfma(K, Q^T)  -> lane holds S[q=lane&31][32 kv vals]
// Swapped PV:   O^T = mfma(V^T, P^T) -> lane-local rescale/normalize.
// exp2-domain softmax (Q pre-scaled by log2e/8); defer-max THR=8.

__device__ __forceinline__ void attn_tile(
    const __bf16* __restrict__ ksb, const __bf16* __restrict__ vsb,
    const bf16x8* qf, int kv0, int q0w, int lq, int hi,
    f32x16& o0, f32x16& o1, float& m, float& l) {
  const int r0 = lq, r1 = 32 + lq;
  const int fx = (lq & 7) ^ ((lq >> 3) << 1);  // matches staging swizzle
  f32x16 s0, s1;
#pragma unroll
  for (int i = 0; i < 16; ++i) { s0[i] = 0.f; s1[i] = 0.f; }
  __builtin_amdgcn_s_setprio(1);
#pragma unroll
  for (int ds = 0; ds < 4; ++ds) {
    const int bb = ((ds * 2 + hi) ^ fx) * 8;
    bf16x8 k0 = *(const bf16x8*)&ksb[r0 * 64 + bb];
    bf16x8 k1 = *(const bf16x8*)&ksb[r1 * 64 + bb];
    s0 = __builtin_amdgcn_mfma_f32_32x32x16_bf16(k0, qf[ds], s0, 0, 0, 0);
    s1 = __builtin_amdgcn_mfma_f32_32x32x16_bf16(k1, qf[ds], s1, 0, 0, 0);
  }
  __builtin_amdgcn_s_setprio(0);

  const int qg = q0w + lq;
  if (kv0 + 63 > q0w) {  // causal mask (log2 domain; -1e30 -> exp2 = 0)
#pragma unroll
    for (int reg = 0; reg < 16; ++reg) {
      const int kvl = (reg & 3) + 8 * (reg >> 2) + 4 * hi;
      if (kv0 + kvl > qg) s0[reg] = -1e30f;
      if (kv0 + 32 + kvl > qg) s1[reg] = -1e30f;
    }
  }
  // tree max over this lane's 32 scores, then combine lane-halves
  float x[8];
#pragma unroll
  for (int i = 0; i < 8; ++i)
    x[i] = fmaxf(fmaxf(s0[i], s0[i + 8]), fmaxf(s1[i], s1[i + 8]));
#pragma unroll
  for (int st = 4; st; st >>= 1)
#pragma unroll
    for (int i = 0; i < st; ++i) x[i] = fmaxf(x[i], x[i + st]);
  const float mx = fmaxf(x[0], __shfl_xor(x[0], 32));

  // defer-max: only rescale when max grew by > 8 (log2 units)
  if (!__all(mx <= m + 8.f)) {
    const float mn = fmaxf(m, mx);
    const float f = __builtin_amdgcn_exp2f(m - mn);
    m = mn;
    l *= f;
#pragma unroll
    for (int i = 0; i < 16; ++i) { o0[i] *= f; o1[i] *= f; }
  }
#pragma unroll
  for (int i = 0; i < 16; ++i) s0[i] = __builtin_amdgcn_exp2f(s0[i] - m);
#pragma unroll
  for (int i = 0; i < 16; ++i) s1[i] = __builtin_amdgcn_exp2f(s1[i] - m);
  float y[8];
#pragma unroll
  for (int i = 0; i < 8; ++i) y[i] = (s0[i] + s0[i + 8]) + (s1[i] + s1[i + 8]);
#pragma unroll
  for (int st = 4; st; st >>= 1)
#pragma unroll
    for (int i = 0; i < st; ++i) y[i] += y[i + st];
  l += y[0] + __shfl_xor(y[0], 32);

  // PV: P repack (cvt_pk + permlane32_swap) -> B-frag; V from LDS as A-frag
#pragma unroll
  for (int ks = 0; ks < 4; ++ks) {
    unsigned pa, pb, pc, pd;
    if (ks < 2) {
      pa = cvt_pk_bf16(s0[ks * 8 + 0], s0[ks * 8 + 1]);
      pb = cvt_pk_bf16(s0[ks * 8 + 2], s0[ks * 8 + 3]);
      pc = cvt_pk_bf16(s0[ks * 8 + 4], s0[ks * 8 + 5]);
      pd = cvt_pk_bf16(s0[ks * 8 + 6], s0[ks * 8 + 7]);
    } else {
      pa = cvt_pk_bf16(s1[(ks - 2) * 8 + 0], s1[(ks - 2) * 8 + 1]);
      pb = cvt_pk_bf16(s1[(ks - 2) * 8 + 2], s1[(ks - 2) * 8 + 3]);
      pc = cvt_pk_bf16(s1[(ks - 2) * 8 + 4], s1[(ks - 2) * 8 + 5]);
      pd = cvt_pk_bf16(s1[(ks - 2) * 8 + 6], s1[(ks - 2) * 8 + 7]);
    }
    asm volatile("v_permlane32_swap_b32 %0, %1" : "+v"(pa), "+v"(pc));
    asm volatile("v_permlane32_swap_b32 %0, %1" : "+v"(pb), "+v"(pd));
    union { unsigned u[4]; bf16x8 v; } pf;
    pf.u[0] = pa; pf.u[1] = pb; pf.u[2] = pc; pf.u[3] = pd;
    const int vb = ((ks * 2 + hi) ^ fx) * 8;
    bf16x8 v0 = *(const bf16x8*)&vsb[r0 * 64 + vb];
    bf16x8 v1 = *(const bf16x8*)&vsb[r1 * 64 + vb];
    o0 = __builtin_amdgcn_mfma_f32_32x32x16_bf16(v0, pf.v, o0, 0, 0, 0);
    o1 = __builtin_amdgcn_mfma_f32_32x32x16_bf16(v1, pf.v, o1, 0, 0, 0);
  }
}

__device__ __forceinline__ void attn_epilogue(
    __bf16* __restrict__ vals, int bh, int q0w, int lq, int hi,
    const f32x16& o0, const f32x16& o1, float l) {
  const float inv = 1.f / l;
  unsigned* outp = (unsigned*)(vals + ((size_t)bh * 2048 + q0w + lq) * 64);
#pragma unroll
  for (int n = 0; n < 2; ++n) {
#pragma unroll
    for (int g = 0; g < 2; ++g) {
      const float e0 = (n ? o1[g * 8 + 0] : o0[g * 8 + 0]) * inv;
      const float e1 = (n ? o1[g * 8 + 1] : o0[g * 8 + 1]) * inv;
      const float e2 = (n ? o1[g * 8 + 2] : o0[g * 8 + 2]) * inv;
      const float e3 = (n ? o1[g * 8 + 3] : o0[g * 8 + 3]) * inv;
      const float e4 = (n ? o1[g * 8 + 4] : o0[g * 8 + 4]) * inv;
      const float e5 = (n ? o1[g * 8 + 5] : o0[g * 8 + 5]) * inv;
      const float e6 = (n ? o1[g * 8 + 6] : o0[g * 8 + 6]) * inv;
      const float e7 = (n ? o1[g * 8 + 7] : o0[g * 8 + 7]) * inv;
      unsigned a = cvt_pk_bf16(e0, e1);
      unsigned a2 = cvt_pk_bf16(e2, e3);
      unsigned b = cvt_pk_bf16(e4, e5);
      unsigned b2 = cvt_pk_bf16(e6, e7);
      asm volatile("v_permlane32_swap_b32 %0, %1" : "+v"(a), "+v"(b));
      asm volatile("v_permlane32_swap_b32 %0, %1" : "+v"(a2), "+v"(b2));
      int4 st = {(int)a, (int)a2, (int)b, (int)b2};
      *(int4*)&outp[(n * 32 + g * 16 + hi * 8) >> 1] = st;
    }
  }
}

__global__ __launch_bounds__(256) void attn_kernel(
    const __bf16* __restrict__ Q, const __bf16* __restrict__ K,
    const __bf16* __restrict__ Vt, __bf16* __restrict__ vals) {
  __shared__ __bf16 Ks[2][4096];
  __shared__ __bf16 Vs[2][4096];  // V^T tile: [d=64][kv=64]
  const int tid = threadIdx.x;
  const int wave = tid >> 6, lane = tid & 63;
  const int lq = lane & 31, hi = lane >> 5;

  // XCD-chunked swizzle: XCD x serves bh in [8x, 8x+8) (KV 8x512KB = L2-sized)
  const int wg = blockIdx.x + (blockIdx.y << 3);  // grid (8, 64)
  const int wgid = (wg & 7) * 64 + (wg >> 3);     // bijective (512 % 8 == 0)
  const int bh = wgid >> 3;
  const int pr = wgid & 7;                        // pair index
  const int qcA = pr, qcB = 15 - pr;              // light / heavy 128-row chunks
  const int q0A = qcA * 128 + wave * 32;
  const int q0B = qcB * 128 + wave * 32;
  const int ntA = 2 * qcA + 2, ntB = 2 * qcB + 2; // ntA <= ntB; total = 34

  bf16x8 qfA[4], qfB[4];
  {
    const __bf16* qpA = Q + ((size_t)bh * 2048 + q0A + lq) * 64 + hi * 8;
    const __bf16* qpB = Q + ((size_t)bh * 2048 + q0B + lq) * 64 + hi * 8;
#pragma unroll
    for (int ds = 0; ds < 4; ++ds) {
      qfA[ds] = *(const bf16x8*)(qpA + ds * 16);
      qfB[ds] = *(const bf16x8*)(qpB + ds * 16);
    }
  }

  f32x16 oA0, oA1, oB0, oB1;
#pragma unroll
  for (int i = 0; i < 16; ++i) { oA0[i] = 0.f; oA1[i] = 0.f; oB0[i] = 0.f; oB1[i] = 0.f; }
  float mA = -3e38f, lA = 0.f, mB = -3e38f, lB = 0.f;

  // staging: 256 threads x 4 x 16B per tile; swizzle f(r)=(r&7)^((r>>3&3)<<1)
  // (invariant under r+=32, so rows sr and sr+32 share the source column)
  const int sr = tid >> 3, sb_ = tid & 7;
  const int sc = (sb_ ^ ((sr & 7) ^ ((sr >> 3) << 1))) * 8;
  const __bf16* Kg0 = K + ((size_t)bh * 2048 + sr) * 64 + sc;
  const __bf16* Kg1 = Kg0 + 32 * 64;
  const __bf16* Vg0 = Vt + ((size_t)bh * 64 + sr) * 2048 + sc;
  const __bf16* Vg1 = Vg0 + 32 * 2048;
  __bf16* KsW = &Ks[0][0] + wave * 512;  // wave-uniform LDS bases
  __bf16* VsW = &Vs[0][0] + wave * 512;

#define STAGE(buf, t)                                                   \
  gload_lds16(Kg0 + (size_t)(t) * 4096, KsW + (buf) * 4096);            \
  gload_lds16(Kg1 + (size_t)(t) * 4096, KsW + (buf) * 4096 + 2048);     \
  gload_lds16(Vg0 + (t) * 64, VsW + (buf) * 4096);                      \
  gload_lds16(Vg1 + (t) * 64, VsW + (buf) * 4096 + 2048);

  STAGE(0, 0);
  __syncthreads();

  for (int t = 0; t < ntB; ++t) {
    const int kv0 = t * 64;
    const int cur = t & 1;
    if (t + 1 < ntB) { STAGE(cur ^ 1, t + 1); }
    const __bf16* ksb = &Ks[cur][0];
    const __bf16* vsb = &Vs[cur][0];
    if (kv0 <= q0B + 31)
      attn_tile(ksb, vsb, qfB, kv0, q0B, lq, hi, oB0, oB1, mB, lB);
    if (t < ntA && kv0 <= q0A + 31)
      attn_tile(ksb, vsb, qfA, kv0, q0A, lq, hi, oA0, oA1, mA, lA);
    __syncthreads();
  }
#undef STAGE

  attn_epilogue(vals, bh, q0B, lq, hi, oB0, oB1, lB);
  attn_epilogue(vals, bh, q0A, lq, hi, oA0, oA1, lA);
}

// ---------------------------------------------------------------- launch
extern "C" void kernel_launch(void* const* d_in, const int* in_sizes, int n_in,
                              void* d_out, int out_size, void* d_ws, size_t ws_size,
                              hipStream_t stream) {
  const float* x = (const float*)d_in[0];
  const float* Wqkv = (const float*)d_in[1];
  const float* bqkv = (const float*)d_in[2];
  const float* Wo = (const float*)d_in[3];
  const float* bo = (const float*)d_in[4];
  float* out = (float*)d_out;
  char* ws = (char*)d_ws;

  // workspace layout (bytes)
  __bf16* xb  = (__bf16*)(ws);                 // 16 MB (x bf16; reused as vals)
  __bf16* Wqt = (__bf16*)(ws + 16777216);      // 6 MB  (W_qkv^T bf16 [3072][1024])
  __bf16* Wot = (__bf16*)(ws + 23068672);      // 2 MB  (W_o^T bf16 [1024][1024])
  __bf16* Qb  = (__bf16*)(ws + 25165824);      // 16 MB ([BH, S, 64], pre-scaled)
  __bf16* Kb  = (__bf16*)(ws + 41943040);      // 16 MB ([BH, S, 64])
  __bf16* Vtb = (__bf16*)(ws + 58720256);      // 16 MB ([BH, 64, S])
  __bf16* vals = xb;                           // attention output (scrambled matrix)

  cvt_bf16_kernel<<<4096, 256, 0, stream>>>(x, xb, 1048576);
  cvt_T_kernel<<<dim3(96, 32), 256, 0, stream>>>(Wqkv, Wqt, 1024, 3072);
  cvt_T_kernel<<<dim3(32, 32), 256, 0, stream>>>(Wo, Wot, 1024, 1024);
  gemm_bt<0><<<dim3(24, 64), 256, 0, stream>>>(xb, Wqt, bqkv, Qb, Kb, Vtb, nullptr);
  attn_kernel<<<dim3(8, 64), 256, 0, stream>>>(Qb, Kb, Vtb, vals);
  gemm_bt<1><<<dim3(8, 64), 256, 0, stream>>>(vals, Wot, bo, nullptr, nullptr, nullptr, out);
}

// Round 4
// 178.991 us; speedup vs baseline: 1.2763x; 1.2763x over previous
//
#include <hip/hip_runtime.h>
#include <hip/hip_bf16.h>
#include <stdint.h>

// MultiHeadAttention fused forward, MI355X/gfx950.
// B=4, S=2048, H=16, hd=64, D=1024. fp32 in/out, bf16 MFMA internally.

typedef __attribute__((ext_vector_type(8))) __bf16 bf16x8;
typedef __attribute__((ext_vector_type(4))) float f32x4;
typedef __attribute__((ext_vector_type(16))) float f32x16;

#define AS_G __attribute__((address_space(1)))
#define AS_L __attribute__((address_space(3)))

__device__ __forceinline__ void gload_lds16(const void* g, void* s) {
  __builtin_amdgcn_global_load_lds((const AS_G void*)g, (AS_L void*)s, 16, 0, 0);
}

__device__ __forceinline__ unsigned cvt_pk_bf16(float lo, float hi) {
  unsigned r;
  asm("v_cvt_pk_bf16_f32 %0, %1, %2" : "=v"(r) : "v"(lo), "v"(hi));
  return r;
}

// ---------------------------------------------------------------- converts
__global__ void cvt_bf16_kernel(const float* __restrict__ in,
                                __bf16* __restrict__ out, int n8) {
  int i = blockIdx.x * blockDim.x + threadIdx.x;
  if (i >= n8) return;
  float4 a = ((const float4*)in)[i * 2];
  float4 b = ((const float4*)in)[i * 2 + 1];
  union { __bf16 h[8]; int4 v; } u;
  u.h[0] = (__bf16)a.x; u.h[1] = (__bf16)a.y; u.h[2] = (__bf16)a.z; u.h[3] = (__bf16)a.w;
  u.h[4] = (__bf16)b.x; u.h[5] = (__bf16)b.y; u.h[6] = (__bf16)b.z; u.h[7] = (__bf16)b.w;
  ((int4*)out)[i] = u.v;
}

// out[n*K + k] = (bf16) in[k*N + n]
__global__ void cvt_T_kernel(const float* __restrict__ in,
                             __bf16* __restrict__ out, int K, int N) {
  __shared__ float tile[32][33];
  int bx = blockIdx.x;  // along N
  int by = blockIdx.y;  // along K
  int tx = threadIdx.x & 31, ty = threadIdx.x >> 5;  // 32 x 8
#pragma unroll
  for (int i = 0; i < 32; i += 8)
    tile[ty + i][tx] = in[(size_t)(by * 32 + ty + i) * N + bx * 32 + tx];
  __syncthreads();
#pragma unroll
  for (int i = 0; i < 32; i += 8)
    out[(size_t)(bx * 32 + ty + i) * K + by * 32 + tx] = (__bf16)tile[tx][ty + i];
}

// ---------------------------------------------------------------- GEMM
// C[M,1024-chunked-N] = A[M,1024] @ Bt[N,1024]^T   (K = 1024 for both GEMMs)
// MODE 0: QKV projection epilogue (scatter Q*(log2e/8) / K / V-transposed, +bias)
// MODE 1: output projection epilogue (fp32 out, +bias)
template <int MODE>
__global__ __launch_bounds__(256) void gemm_bt(
    const __bf16* __restrict__ A, const __bf16* __restrict__ Bt,
    const float* __restrict__ bias,
    __bf16* __restrict__ Qb, __bf16* __restrict__ Kb, __bf16* __restrict__ Vtb,
    float* __restrict__ Out) {
  __shared__ __bf16 As[128 * 32];
  __shared__ __bf16 Bs[128 * 32];
  const int tid = threadIdx.x;
  const int wave = tid >> 6, lane = tid & 63;
  const int lhi = lane >> 4, llo = lane & 15;
  const int wm = wave >> 1, wn = wave & 1;
  const int m0 = blockIdx.y * 128, n0 = blockIdx.x * 128;

  const int srow = lane >> 2;         // 0..15 within a 16-row issue
  const int scol = (lane & 3) * 8;    // element column (x8 bf16 = 16B)
  const __bf16* Ag0 = A + (size_t)(m0 + (wave * 2 + 0) * 16 + srow) * 1024 + scol;
  const __bf16* Ag1 = A + (size_t)(m0 + (wave * 2 + 1) * 16 + srow) * 1024 + scol;
  const __bf16* Bg0 = Bt + (size_t)(n0 + (wave * 2 + 0) * 16 + srow) * 1024 + scol;
  const __bf16* Bg1 = Bt + (size_t)(n0 + (wave * 2 + 1) * 16 + srow) * 1024 + scol;
  __bf16* As0 = As + (wave * 2 + 0) * 512;
  __bf16* As1 = As + (wave * 2 + 1) * 512;
  __bf16* Bs0 = Bs + (wave * 2 + 0) * 512;
  __bf16* Bs1 = Bs + (wave * 2 + 1) * 512;

  f32x4 acc[4][4];
#pragma unroll
  for (int m = 0; m < 4; ++m)
#pragma unroll
    for (int n = 0; n < 4; ++n) acc[m][n] = (f32x4){0.f, 0.f, 0.f, 0.f};

  for (int k0 = 0; k0 < 1024; k0 += 32) {
    gload_lds16(Ag0 + k0, As0);
    gload_lds16(Ag1 + k0, As1);
    gload_lds16(Bg0 + k0, Bs0);
    gload_lds16(Bg1 + k0, Bs1);
    __syncthreads();
    bf16x8 af[4], bfr[4];
#pragma unroll
    for (int i = 0; i < 4; ++i)
      af[i] = *(const bf16x8*)&As[(wm * 64 + i * 16 + llo) * 32 + lhi * 8];
#pragma unroll
    for (int i = 0; i < 4; ++i)
      bfr[i] = *(const bf16x8*)&Bs[(wn * 64 + i * 16 + llo) * 32 + lhi * 8];
#pragma unroll
    for (int m = 0; m < 4; ++m)
#pragma unroll
      for (int n = 0; n < 4; ++n)
        acc[m][n] = __builtin_amdgcn_mfma_f32_16x16x32_bf16(af[m], bfr[n],
                                                            acc[m][n], 0, 0, 0);
    __syncthreads();
  }

#pragma unroll
  for (int ni = 0; ni < 4; ++ni) {
    const int col = n0 + wn * 64 + ni * 16 + llo;
    const float bv = bias[col];
    if (MODE == 0) {
      const int h = col / 192, rem = col % 192;
#pragma unroll
      for (int mi = 0; mi < 4; ++mi) {
        const int row0 = m0 + wm * 64 + mi * 16 + lhi * 4;
        const int b = row0 >> 11;
        const int s0 = row0 & 2047;
        const int bh = b * 16 + h;
        f32x4 v = acc[mi][ni];
        if (rem < 64) {
          // Q pre-scaled by (1/sqrt(64)) * log2(e) for exp2-domain softmax
#pragma unroll
          for (int r = 0; r < 4; ++r)
            Qb[((size_t)bh * 2048 + s0 + r) * 64 + rem] =
                (__bf16)((v[r] + bv) * 0.18033688011112042f);
        } else if (rem < 128) {
#pragma unroll
          for (int r = 0; r < 4; ++r)
            Kb[((size_t)bh * 2048 + s0 + r) * 64 + (rem - 64)] = (__bf16)(v[r] + bv);
        } else {
          union { __bf16 h4[4]; int2 v2; } u;
#pragma unroll
          for (int r = 0; r < 4; ++r) u.h4[r] = (__bf16)(v[r] + bv);
          *(int2*)&Vtb[((size_t)bh * 64 + (rem - 128)) * 2048 + s0] = u.v2;
        }
      }
    } else {
#pragma unroll
      for (int mi = 0; mi < 4; ++mi) {
        const int row0 = m0 + wm * 64 + mi * 16 + lhi * 4;
        f32x4 v = acc[mi][ni];
#pragma unroll
        for (int r = 0; r < 4; ++r)
          Out[(size_t)(row0 + r) * 1024 + col] = v[r] + bv;
      }
    }
  }
}

// ---------------------------------------------------------------- attention
// 4 waves x 32 q-rows = 128-row chunk per block; 1024 blocks (4/CU).
// Swapped QK^T: S^T = mfma(K, Q^T)  -> lane holds S[q=lane&31][32 kv vals]
// Swapped PV:   O^T = mfma(V^T, P^T) -> lane-local rescale/normalize.
// exp2-domain softmax (Q pre-scaled by log2e/8); defer-max THR=8.

__device__ __forceinline__ void attn_tile(
    const __bf16* __restrict__ ksb, const __bf16* __restrict__ vsb,
    const bf16x8* qf, int kv0, int q0w, int lq, int hi,
    f32x16& o0, f32x16& o1, float& m, float& l) {
  const int r0 = lq, r1 = 32 + lq;
  const int fx = (lq & 7) ^ ((lq >> 3) << 1);  // matches staging swizzle
  f32x16 s0, s1;
#pragma unroll
  for (int i = 0; i < 16; ++i) { s0[i] = 0.f; s1[i] = 0.f; }
  __builtin_amdgcn_s_setprio(1);
#pragma unroll
  for (int ds = 0; ds < 4; ++ds) {
    const int bb = ((ds * 2 + hi) ^ fx) * 8;
    bf16x8 k0 = *(const bf16x8*)&ksb[r0 * 64 + bb];
    bf16x8 k1 = *(const bf16x8*)&ksb[r1 * 64 + bb];
    s0 = __builtin_amdgcn_mfma_f32_32x32x16_bf16(k0, qf[ds], s0, 0, 0, 0);
    s1 = __builtin_amdgcn_mfma_f32_32x32x16_bf16(k1, qf[ds], s1, 0, 0, 0);
  }
  __builtin_amdgcn_s_setprio(0);

  const int qg = q0w + lq;
  if (kv0 + 63 > q0w) {  // causal mask (log2 domain; -1e30 -> exp2 = 0)
#pragma unroll
    for (int reg = 0; reg < 16; ++reg) {
      const int kvl = (reg & 3) + 8 * (reg >> 2) + 4 * hi;
      if (kv0 + kvl > qg) s0[reg] = -1e30f;
      if (kv0 + 32 + kvl > qg) s1[reg] = -1e30f;
    }
  }
  // tree max over this lane's 32 scores, then combine lane-halves
  float x[8];
#pragma unroll
  for (int i = 0; i < 8; ++i)
    x[i] = fmaxf(fmaxf(s0[i], s0[i + 8]), fmaxf(s1[i], s1[i + 8]));
#pragma unroll
  for (int st = 4; st; st >>= 1)
#pragma unroll
    for (int i = 0; i < st; ++i) x[i] = fmaxf(x[i], x[i + st]);
  const float mx = fmaxf(x[0], __shfl_xor(x[0], 32));

  // defer-max: only rescale when max grew by > 8 (log2 units)
  if (!__all(mx <= m + 8.f)) {
    const float mn = fmaxf(m, mx);
    const float f = __builtin_amdgcn_exp2f(m - mn);
    m = mn;
    l *= f;
#pragma unroll
    for (int i = 0; i < 16; ++i) { o0[i] *= f; o1[i] *= f; }
  }
#pragma unroll
  for (int i = 0; i < 16; ++i) s0[i] = __builtin_amdgcn_exp2f(s0[i] - m);
#pragma unroll
  for (int i = 0; i < 16; ++i) s1[i] = __builtin_amdgcn_exp2f(s1[i] - m);
  float y[8];
#pragma unroll
  for (int i = 0; i < 8; ++i) y[i] = (s0[i] + s0[i + 8]) + (s1[i] + s1[i + 8]);
#pragma unroll
  for (int st = 4; st; st >>= 1)
#pragma unroll
    for (int i = 0; i < st; ++i) y[i] += y[i + st];
  l += y[0] + __shfl_xor(y[0], 32);

  // PV: P repack (cvt_pk + permlane32_swap) -> B-frag; V from LDS as A-frag
#pragma unroll
  for (int ks = 0; ks < 4; ++ks) {
    unsigned pa, pb, pc, pd;
    if (ks < 2) {
      pa = cvt_pk_bf16(s0[ks * 8 + 0], s0[ks * 8 + 1]);
      pb = cvt_pk_bf16(s0[ks * 8 + 2], s0[ks * 8 + 3]);
      pc = cvt_pk_bf16(s0[ks * 8 + 4], s0[ks * 8 + 5]);
      pd = cvt_pk_bf16(s0[ks * 8 + 6], s0[ks * 8 + 7]);
    } else {
      pa = cvt_pk_bf16(s1[(ks - 2) * 8 + 0], s1[(ks - 2) * 8 + 1]);
      pb = cvt_pk_bf16(s1[(ks - 2) * 8 + 2], s1[(ks - 2) * 8 + 3]);
      pc = cvt_pk_bf16(s1[(ks - 2) * 8 + 4], s1[(ks - 2) * 8 + 5]);
      pd = cvt_pk_bf16(s1[(ks - 2) * 8 + 6], s1[(ks - 2) * 8 + 7]);
    }
    asm volatile("v_permlane32_swap_b32 %0, %1" : "+v"(pa), "+v"(pc));
    asm volatile("v_permlane32_swap_b32 %0, %1" : "+v"(pb), "+v"(pd));
    union { unsigned u[4]; bf16x8 v; } pf;
    pf.u[0] = pa; pf.u[1] = pb; pf.u[2] = pc; pf.u[3] = pd;
    const int vb = ((ks * 2 + hi) ^ fx) * 8;
    bf16x8 v0 = *(const bf16x8*)&vsb[r0 * 64 + vb];
    bf16x8 v1 = *(const bf16x8*)&vsb[r1 * 64 + vb];
    o0 = __builtin_amdgcn_mfma_f32_32x32x16_bf16(v0, pf.v, o0, 0, 0, 0);
    o1 = __builtin_amdgcn_mfma_f32_32x32x16_bf16(v1, pf.v, o1, 0, 0, 0);
  }
}

__device__ __forceinline__ void attn_epilogue(
    __bf16* __restrict__ vals, int bh, int q0w, int lq, int hi,
    const f32x16& o0, const f32x16& o1, float l) {
  const float inv = 1.f / l;
  unsigned* outp = (unsigned*)(vals + ((size_t)bh * 2048 + q0w + lq) * 64);
#pragma unroll
  for (int n = 0; n < 2; ++n) {
#pragma unroll
    for (int g = 0; g < 2; ++g) {
      const float e0 = (n ? o1[g * 8 + 0] : o0[g * 8 + 0]) * inv;
      const float e1 = (n ? o1[g * 8 + 1] : o0[g * 8 + 1]) * inv;
      const float e2 = (n ? o1[g * 8 + 2] : o0[g * 8 + 2]) * inv;
      const float e3 = (n ? o1[g * 8 + 3] : o0[g * 8 + 3]) * inv;
      const float e4 = (n ? o1[g * 8 + 4] : o0[g * 8 + 4]) * inv;
      const float e5 = (n ? o1[g * 8 + 5] : o0[g * 8 + 5]) * inv;
      const float e6 = (n ? o1[g * 8 + 6] : o0[g * 8 + 6]) * inv;
      const float e7 = (n ? o1[g * 8 + 7] : o0[g * 8 + 7]) * inv;
      unsigned a = cvt_pk_bf16(e0, e1);
      unsigned a2 = cvt_pk_bf16(e2, e3);
      unsigned b = cvt_pk_bf16(e4, e5);
      unsigned b2 = cvt_pk_bf16(e6, e7);
      asm volatile("v_permlane32_swap_b32 %0, %1" : "+v"(a), "+v"(b));
      asm volatile("v_permlane32_swap_b32 %0, %1" : "+v"(a2), "+v"(b2));
      int4 st = {(int)a, (int)a2, (int)b, (int)b2};
      *(int4*)&outp[(n * 32 + g * 16 + hi * 8) >> 1] = st;
    }
  }
}

__global__ __launch_bounds__(256) void attn_kernel(
    const __bf16* __restrict__ Q, const __bf16* __restrict__ K,
    const __bf16* __restrict__ Vt, __bf16* __restrict__ vals) {
  __shared__ __bf16 Ks[2][4096];
  __shared__ __bf16 Vs[2][4096];  // V^T tile: [d=64][kv=64]
  const int tid = threadIdx.x;
  const int wave = tid >> 6, lane = tid & 63;
  const int lq = lane & 31, hi = lane >> 5;

  // XCD-chunked + heavy-first (LPT) dispatch:
  // XCD x gets bh in [8x,8x+8) x all 16 chunks; chunk 15 (32 tiles) first.
  const int wg = blockIdx.x + (blockIdx.y << 3);  // grid (8, 128) -> 0..1023
  const int wgid = (wg & 7) * 128 + (wg >> 3);    // bijective (1024 % 8 == 0)
  const int local = wgid & 127;
  const int bh = (wgid >> 7) * 8 + (local & 7);
  const int qc = 15 - (local >> 3);               // chunk 15 dispatched first
  const int q0w = qc * 128 + wave * 32;
  const int nt = 2 * qc + 2;

  bf16x8 qf[4];
  {
    const __bf16* qp = Q + ((size_t)bh * 2048 + q0w + lq) * 64 + hi * 8;
#pragma unroll
    for (int ds = 0; ds < 4; ++ds) qf[ds] = *(const bf16x8*)(qp + ds * 16);
  }

  f32x16 o0, o1;
#pragma unroll
  for (int i = 0; i < 16; ++i) { o0[i] = 0.f; o1[i] = 0.f; }
  float m = -3e38f, l = 0.f;

  // staging: 256 threads x 4 x 16B per tile; swizzle f(r)=(r&7)^((r>>3&3)<<1)
  // (invariant under r+=32, so rows sr and sr+32 share the source column)
  const int sr = tid >> 3, sb_ = tid & 7;
  const int sc = (sb_ ^ ((sr & 7) ^ ((sr >> 3) << 1))) * 8;
  const __bf16* Kg0 = K + ((size_t)bh * 2048 + sr) * 64 + sc;
  const __bf16* Kg1 = Kg0 + 32 * 64;
  const __bf16* Vg0 = Vt + ((size_t)bh * 64 + sr) * 2048 + sc;
  const __bf16* Vg1 = Vg0 + 32 * 2048;
  __bf16* KsW = &Ks[0][0] + wave * 512;  // wave-uniform LDS bases
  __bf16* VsW = &Vs[0][0] + wave * 512;

#define STAGE(buf, t)                                                   \
  gload_lds16(Kg0 + (size_t)(t) * 4096, KsW + (buf) * 4096);            \
  gload_lds16(Kg1 + (size_t)(t) * 4096, KsW + (buf) * 4096 + 2048);     \
  gload_lds16(Vg0 + (t) * 64, VsW + (buf) * 4096);                      \
  gload_lds16(Vg1 + (t) * 64, VsW + (buf) * 4096 + 2048);

  STAGE(0, 0);
  __syncthreads();

  for (int t = 0; t < nt; ++t) {
    const int cur = t & 1;
    if (t + 1 < nt) { STAGE(cur ^ 1, t + 1); }
    attn_tile(&Ks[cur][0], &Vs[cur][0], qf, t * 64, q0w, lq, hi, o0, o1, m, l);
    __syncthreads();
  }
#undef STAGE

  attn_epilogue(vals, bh, q0w, lq, hi, o0, o1, l);
}

// ---------------------------------------------------------------- launch
extern "C" void kernel_launch(void* const* d_in, const int* in_sizes, int n_in,
                              void* d_out, int out_size, void* d_ws, size_t ws_size,
                              hipStream_t stream) {
  const float* x = (const float*)d_in[0];
  const float* Wqkv = (const float*)d_in[1];
  const float* bqkv = (const float*)d_in[2];
  const float* Wo = (const float*)d_in[3];
  const float* bo = (const float*)d_in[4];
  float* out = (float*)d_out;
  char* ws = (char*)d_ws;

  // workspace layout (bytes)
  __bf16* xb  = (__bf16*)(ws);                 // 16 MB (x bf16; reused as vals)
  __bf16* Wqt = (__bf16*)(ws + 16777216);      // 6 MB  (W_qkv^T bf16 [3072][1024])
  __bf16* Wot = (__bf16*)(ws + 23068672);      // 2 MB  (W_o^T bf16 [1024][1024])
  __bf16* Qb  = (__bf16*)(ws + 25165824);      // 16 MB ([BH, S, 64], pre-scaled)
  __bf16* Kb  = (__bf16*)(ws + 41943040);      // 16 MB ([BH, S, 64])
  __bf16* Vtb = (__bf16*)(ws + 58720256);      // 16 MB ([BH, 64, S])
  __bf16* vals = xb;                           // attention output (scrambled matrix)

  cvt_bf16_kernel<<<4096, 256, 0, stream>>>(x, xb, 1048576);
  cvt_T_kernel<<<dim3(96, 32), 256, 0, stream>>>(Wqkv, Wqt, 1024, 3072);
  cvt_T_kernel<<<dim3(32, 32), 256, 0, stream>>>(Wo, Wot, 1024, 1024);
  gemm_bt<0><<<dim3(24, 64), 256, 0, stream>>>(xb, Wqt, bqkv, Qb, Kb, Vtb, nullptr);
  attn_kernel<<<dim3(8, 128), 256, 0, stream>>>(Qb, Kb, Vtb, vals);
  gemm_bt<1><<<dim3(8, 64), 256, 0, stream>>>(vals, Wot, bo, nullptr, nullptr, nullptr, out);
}

// Round 5
// 176.435 us; speedup vs baseline: 1.2948x; 1.0145x over previous
//
#include <hip/hip_runtime.h>
#include <hip/hip_bf16.h>
#include <stdint.h>

// MultiHeadAttention fused forward, MI355X/gfx950.
// B=4, S=2048, H=16, hd=64, D=1024. fp32 in/out, bf16 MFMA internally.

typedef __attribute__((ext_vector_type(8))) __bf16 bf16x8;
typedef __attribute__((ext_vector_type(4))) float f32x4;
typedef __attribute__((ext_vector_type(16))) float f32x16;

#define AS_G __attribute__((address_space(1)))
#define AS_L __attribute__((address_space(3)))

__device__ __forceinline__ void gload_lds16(const void* g, void* s) {
  __builtin_amdgcn_global_load_lds((const AS_G void*)g, (AS_L void*)s, 16, 0, 0);
}

__device__ __forceinline__ unsigned cvt_pk_bf16(float lo, float hi) {
  unsigned r;
  asm("v_cvt_pk_bf16_f32 %0, %1, %2" : "=v"(r) : "v"(lo), "v"(hi));
  return r;
}

// ---------------------------------------------------------------- converts
__global__ void cvt_bf16_kernel(const float* __restrict__ in,
                                __bf16* __restrict__ out, int n8) {
  int i = blockIdx.x * blockDim.x + threadIdx.x;
  if (i >= n8) return;
  float4 a = ((const float4*)in)[i * 2];
  float4 b = ((const float4*)in)[i * 2 + 1];
  union { __bf16 h[8]; int4 v; } u;
  u.h[0] = (__bf16)a.x; u.h[1] = (__bf16)a.y; u.h[2] = (__bf16)a.z; u.h[3] = (__bf16)a.w;
  u.h[4] = (__bf16)b.x; u.h[5] = (__bf16)b.y; u.h[6] = (__bf16)b.z; u.h[7] = (__bf16)b.w;
  ((int4*)out)[i] = u.v;
}

// out[n*K + k] = (bf16) in[k*N + n]
__global__ void cvt_T_kernel(const float* __restrict__ in,
                             __bf16* __restrict__ out, int K, int N) {
  __shared__ float tile[32][33];
  int bx = blockIdx.x;  // along N
  int by = blockIdx.y;  // along K
  int tx = threadIdx.x & 31, ty = threadIdx.x >> 5;  // 32 x 8
#pragma unroll
  for (int i = 0; i < 32; i += 8)
    tile[ty + i][tx] = in[(size_t)(by * 32 + ty + i) * N + bx * 32 + tx];
  __syncthreads();
#pragma unroll
  for (int i = 0; i < 32; i += 8)
    out[(size_t)(bx * 32 + ty + i) * K + by * 32 + tx] = (__bf16)tile[tx][ty + i];
}

// ---------------------------------------------------------------- GEMM
// Counted-vmcnt 4-phase pipelined 128x128 tile, BK=64, 4 waves (2x2),
// double-buffered 64KB LDS, conflict-free XOR-swizzled layout.
// C[M,N] = A[M,1024] @ Bt[N,1024]^T  (K = 1024)
// LDS layout per buffer c: A at c*16K, B at 32K + c*16K.
//   Within: ks*8192 + v*128 + (w ^ (v&7))*16, where row r -> v=r>>1,
//   w = (r&1)*4 + u2 (u2 = 16B unit within the 32-col K-half).
// Staging writes LDS LINEARLY (global_load_lds) with inverse-swizzled
// global source (rule 21); reads apply the swizzle -> conflict-free.
// Schedule per iteration (tiles T=2i in buf0, T+1 in buf1), 4 phases:
//   ph0: compute(buf0,ks0); stage G(T+1,ks1)->buf1
//   ph1: compute(buf0,ks1); stage G(T+2,ks0)->buf0
//   ph2: compute(buf1,ks0); stage G(T+2,ks1)->buf0
//   ph3: compute(buf1,ks1); stage G(T+3,ks0)->buf1
// vmcnt(8) before every barrier (2 groups always in flight, never 0).
// MODE 0: QKV projection epilogue (scatter Q*(log2e/8) / K / V^T, +bias)
// MODE 1: output projection epilogue (fp32 out, +bias)
template <int MODE, int NT, int NBLK>
__global__ __launch_bounds__(256, 2) void gemm_bt(
    const __bf16* __restrict__ A, const __bf16* __restrict__ Bt,
    const float* __restrict__ bias,
    __bf16* __restrict__ Qb, __bf16* __restrict__ Kb, __bf16* __restrict__ Vtb,
    float* __restrict__ Out) {
  __shared__ char lds[65536];
  const int tid = threadIdx.x;
  const int wave = tid >> 6, lane = tid & 63;
  const int lhi = lane >> 4, llo = lane & 15;
  const int wm = wave >> 1, wn = wave & 1;

  const int wg = blockIdx.x + blockIdx.y * gridDim.x;
  const int wgid = (wg & 7) * (NBLK >> 3) + (wg >> 3);  // XCD-chunked, bijective
  const int m0 = (wgid / NT) * 128, n0 = (wgid % NT) * 128;

  // staging source precompute: line j covers linear LDS idx = j*256 + tid.
  // v = idx>>3, wl = idx&7, wg_ = wl ^ (v&7), r = 2v + (wg_>>2), u2 = wg_&3
  int S[2];
#pragma unroll
  for (int j = 0; j < 2; ++j) {
    const int idx = j * 256 + tid;
    const int v = idx >> 3, wl = idx & 7;
    const int wg_ = wl ^ (v & 7);
    const int r = (v << 1) | (wg_ >> 2), u2 = wg_ & 3;
    S[j] = r * 1024 + u2 * 8;  // element offset (row-major, stride K=1024)
  }
  const __bf16* Asrc = A + (size_t)m0 * 1024;
  const __bf16* Bsrc = Bt + (size_t)n0 * 1024;
  const int dstw = wave * 1024;  // wave-uniform LDS byte offset within line

  auto stageAB = [&](int c, int t, int ks) {
    char* ab = &lds[c * 16384 + ks * 8192];
    char* bb = &lds[32768 + c * 16384 + ks * 8192];
    const int go = t * 64 + ks * 32;
    gload_lds16(Asrc + S[0] + go, ab + dstw);
    gload_lds16(Asrc + S[1] + go, ab + 4096 + dstw);
    gload_lds16(Bsrc + S[0] + go, bb + dstw);
    gload_lds16(Bsrc + S[1] + go, bb + 4096 + dstw);
  };

  f32x4 acc[4][4];
#pragma unroll
  for (int mi = 0; mi < 4; ++mi)
#pragma unroll
    for (int nj = 0; nj < 4; ++nj) acc[mi][nj] = (f32x4){0.f, 0.f, 0.f, 0.f};

  // fragment LDS offsets (swizzled reads)
  auto aoff = [&](int c, int ks, int mi) {
    const int r = wm * 64 + mi * 16 + llo;
    const int v = r >> 1;
    const int w = ((r & 1) << 2) | lhi;
    return c * 16384 + ks * 8192 + v * 128 + ((w ^ (v & 7)) << 4);
  };
  auto boff = [&](int c, int ks, int nj) {
    const int r = wn * 64 + nj * 16 + llo;
    const int v = r >> 1;
    const int w = ((r & 1) << 2) | lhi;
    return 32768 + c * 16384 + ks * 8192 + v * 128 + ((w ^ (v & 7)) << 4);
  };

  auto phase = [&](int c, int ks, int sc, int st, int sks) {
    bf16x8 fa[4], fb[4];
#pragma unroll
    for (int mi = 0; mi < 4; ++mi) fa[mi] = *(const bf16x8*)&lds[aoff(c, ks, mi)];
#pragma unroll
    for (int nj = 0; nj < 4; ++nj) fb[nj] = *(const bf16x8*)&lds[boff(c, ks, nj)];
    stageAB(sc, st, sks);
    __builtin_amdgcn_sched_barrier(0);
    asm volatile("s_waitcnt vmcnt(8)" ::: "memory");
    __builtin_amdgcn_sched_barrier(0);
    __builtin_amdgcn_s_barrier();
    __builtin_amdgcn_s_setprio(1);
#pragma unroll
    for (int mi = 0; mi < 4; ++mi)
#pragma unroll
      for (int nj = 0; nj < 4; ++nj)
        acc[mi][nj] = __builtin_amdgcn_mfma_f32_16x16x32_bf16(fa[mi], fb[nj],
                                                              acc[mi][nj], 0, 0, 0);
    __builtin_amdgcn_s_setprio(0);
    __builtin_amdgcn_sched_barrier(0);
    __builtin_amdgcn_s_barrier();
  };

  // prologue: stage G(0,ks0), G(0,ks1), G(1,ks0); keep newest 8 in flight
  stageAB(0, 0, 0);
  stageAB(0, 0, 1);
  stageAB(1, 1, 0);
  __builtin_amdgcn_sched_barrier(0);
  asm volatile("s_waitcnt vmcnt(8)" ::: "memory");
  __builtin_amdgcn_sched_barrier(0);
  __builtin_amdgcn_s_barrier();

  for (int it = 0; it < 8; ++it) {
    const int T = 2 * it;
    phase(0, 0, 1, (T + 1) & 15, 1);
    phase(0, 1, 0, (T + 2) & 15, 0);
    phase(1, 0, 0, (T + 2) & 15, 1);
    phase(1, 1, 1, (T + 3) & 15, 0);
  }

  // ------------------------------------------------------------ epilogue
#pragma unroll
  for (int nj = 0; nj < 4; ++nj) {
    const int col = n0 + wn * 64 + nj * 16 + llo;
    const float bv = bias[col];
    if (MODE == 0) {
      const int h = col / 192, rem = col % 192;
#pragma unroll
      for (int mi = 0; mi < 4; ++mi) {
        const int row0 = m0 + wm * 64 + mi * 16 + lhi * 4;
        const int b = row0 >> 11;
        const int s0 = row0 & 2047;
        const int bh = b * 16 + h;
        f32x4 v = acc[mi][nj];
        if (rem < 64) {
          // Q pre-scaled by (1/sqrt(64)) * log2(e) for exp2-domain softmax
#pragma unroll
          for (int r = 0; r < 4; ++r)
            Qb[((size_t)bh * 2048 + s0 + r) * 64 + rem] =
                (__bf16)((v[r] + bv) * 0.18033688011112042f);
        } else if (rem < 128) {
#pragma unroll
          for (int r = 0; r < 4; ++r)
            Kb[((size_t)bh * 2048 + s0 + r) * 64 + (rem - 64)] = (__bf16)(v[r] + bv);
        } else {
          union { __bf16 h4[4]; int2 v2; } u;
#pragma unroll
          for (int r = 0; r < 4; ++r) u.h4[r] = (__bf16)(v[r] + bv);
          *(int2*)&Vtb[((size_t)bh * 64 + (rem - 128)) * 2048 + s0] = u.v2;
        }
      }
    } else {
#pragma unroll
      for (int mi = 0; mi < 4; ++mi) {
        const int row0 = m0 + wm * 64 + mi * 16 + lhi * 4;
        f32x4 v = acc[mi][nj];
#pragma unroll
        for (int r = 0; r < 4; ++r)
          Out[(size_t)(row0 + r) * 1024 + col] = v[r] + bv;
      }
    }
  }
}

// ---------------------------------------------------------------- attention
// 4 waves x 32 q-rows = 128-row chunk per block; 1024 blocks (4/CU).
// Swapped QK^T: S^T = mfma(K, Q^T)  -> lane holds S[q=lane&31][32 kv vals]
// Swapped PV:   O^T = mfma(V^T, P^T) -> lane-local rescale/normalize.
// exp2-domain softmax (Q pre-scaled by log2e/8); defer-max THR=8.

__device__ __forceinline__ void attn_tile(
    const __bf16* __restrict__ ksb, const __bf16* __restrict__ vsb,
    const bf16x8* qf, int kv0, int q0w, int lq, int hi,
    f32x16& o0, f32x16& o1, float& m, float& l) {
  const int r0 = lq, r1 = 32 + lq;
  const int fx = (lq & 7) ^ ((lq >> 3) << 1);  // matches staging swizzle
  f32x16 s0, s1;
#pragma unroll
  for (int i = 0; i < 16; ++i) { s0[i] = 0.f; s1[i] = 0.f; }
  __builtin_amdgcn_s_setprio(1);
#pragma unroll
  for (int ds = 0; ds < 4; ++ds) {
    const int bb = ((ds * 2 + hi) ^ fx) * 8;
    bf16x8 k0 = *(const bf16x8*)&ksb[r0 * 64 + bb];
    bf16x8 k1 = *(const bf16x8*)&ksb[r1 * 64 + bb];
    s0 = __builtin_amdgcn_mfma_f32_32x32x16_bf16(k0, qf[ds], s0, 0, 0, 0);
    s1 = __builtin_amdgcn_mfma_f32_32x32x16_bf16(k1, qf[ds], s1, 0, 0, 0);
  }
  __builtin_amdgcn_s_setprio(0);

  const int qg = q0w + lq;
  if (kv0 + 63 > q0w) {  // causal mask (log2 domain; -1e30 -> exp2 = 0)
#pragma unroll
    for (int reg = 0; reg < 16; ++reg) {
      const int kvl = (reg & 3) + 8 * (reg >> 2) + 4 * hi;
      if (kv0 + kvl > qg) s0[reg] = -1e30f;
      if (kv0 + 32 + kvl > qg) s1[reg] = -1e30f;
    }
  }
  // tree max over this lane's 32 scores, then combine lane-halves
  float x[8];
#pragma unroll
  for (int i = 0; i < 8; ++i)
    x[i] = fmaxf(fmaxf(s0[i], s0[i + 8]), fmaxf(s1[i], s1[i + 8]));
#pragma unroll
  for (int st = 4; st; st >>= 1)
#pragma unroll
    for (int i = 0; i < st; ++i) x[i] = fmaxf(x[i], x[i + st]);
  const float mx = fmaxf(x[0], __shfl_xor(x[0], 32));

  // defer-max: only rescale when max grew by > 8 (log2 units)
  if (!__all(mx <= m + 8.f)) {
    const float mn = fmaxf(m, mx);
    const float f = __builtin_amdgcn_exp2f(m - mn);
    m = mn;
    l *= f;
#pragma unroll
    for (int i = 0; i < 16; ++i) { o0[i] *= f; o1[i] *= f; }
  }
#pragma unroll
  for (int i = 0; i < 16; ++i) s0[i] = __builtin_amdgcn_exp2f(s0[i] - m);
#pragma unroll
  for (int i = 0; i < 16; ++i) s1[i] = __builtin_amdgcn_exp2f(s1[i] - m);
  float y[8];
#pragma unroll
  for (int i = 0; i < 8; ++i) y[i] = (s0[i] + s0[i + 8]) + (s1[i] + s1[i + 8]);
#pragma unroll
  for (int st = 4; st; st >>= 1)
#pragma unroll
    for (int i = 0; i < st; ++i) y[i] += y[i + st];
  l += y[0] + __shfl_xor(y[0], 32);

  // PV: P repack (cvt_pk + permlane32_swap) -> B-frag; V from LDS as A-frag
#pragma unroll
  for (int ks = 0; ks < 4; ++ks) {
    unsigned pa, pb, pc, pd;
    if (ks < 2) {
      pa = cvt_pk_bf16(s0[ks * 8 + 0], s0[ks * 8 + 1]);
      pb = cvt_pk_bf16(s0[ks * 8 + 2], s0[ks * 8 + 3]);
      pc = cvt_pk_bf16(s0[ks * 8 + 4], s0[ks * 8 + 5]);
      pd = cvt_pk_bf16(s0[ks * 8 + 6], s0[ks * 8 + 7]);
    } else {
      pa = cvt_pk_bf16(s1[(ks - 2) * 8 + 0], s1[(ks - 2) * 8 + 1]);
      pb = cvt_pk_bf16(s1[(ks - 2) * 8 + 2], s1[(ks - 2) * 8 + 3]);
      pc = cvt_pk_bf16(s1[(ks - 2) * 8 + 4], s1[(ks - 2) * 8 + 5]);
      pd = cvt_pk_bf16(s1[(ks - 2) * 8 + 6], s1[(ks - 2) * 8 + 7]);
    }
    asm volatile("v_permlane32_swap_b32 %0, %1" : "+v"(pa), "+v"(pc));
    asm volatile("v_permlane32_swap_b32 %0, %1" : "+v"(pb), "+v"(pd));
    union { unsigned u[4]; bf16x8 v; } pf;
    pf.u[0] = pa; pf.u[1] = pb; pf.u[2] = pc; pf.u[3] = pd;
    const int vb = ((ks * 2 + hi) ^ fx) * 8;
    bf16x8 v0 = *(const bf16x8*)&vsb[r0 * 64 + vb];
    bf16x8 v1 = *(const bf16x8*)&vsb[r1 * 64 + vb];
    o0 = __builtin_amdgcn_mfma_f32_32x32x16_bf16(v0, pf.v, o0, 0, 0, 0);
    o1 = __builtin_amdgcn_mfma_f32_32x32x16_bf16(v1, pf.v, o1, 0, 0, 0);
  }
}

__device__ __forceinline__ void attn_epilogue(
    __bf16* __restrict__ vals, int bh, int q0w, int lq, int hi,
    const f32x16& o0, const f32x16& o1, float l) {
  const float inv = 1.f / l;
  unsigned* outp = (unsigned*)(vals + ((size_t)bh * 2048 + q0w + lq) * 64);
#pragma unroll
  for (int n = 0; n < 2; ++n) {
#pragma unroll
    for (int g = 0; g < 2; ++g) {
      const float e0 = (n ? o1[g * 8 + 0] : o0[g * 8 + 0]) * inv;
      const float e1 = (n ? o1[g * 8 + 1] : o0[g * 8 + 1]) * inv;
      const float e2 = (n ? o1[g * 8 + 2] : o0[g * 8 + 2]) * inv;
      const float e3 = (n ? o1[g * 8 + 3] : o0[g * 8 + 3]) * inv;
      const float e4 = (n ? o1[g * 8 + 4] : o0[g * 8 + 4]) * inv;
      const float e5 = (n ? o1[g * 8 + 5] : o0[g * 8 + 5]) * inv;
      const float e6 = (n ? o1[g * 8 + 6] : o0[g * 8 + 6]) * inv;
      const float e7 = (n ? o1[g * 8 + 7] : o0[g * 8 + 7]) * inv;
      unsigned a = cvt_pk_bf16(e0, e1);
      unsigned a2 = cvt_pk_bf16(e2, e3);
      unsigned b = cvt_pk_bf16(e4, e5);
      unsigned b2 = cvt_pk_bf16(e6, e7);
      asm volatile("v_permlane32_swap_b32 %0, %1" : "+v"(a), "+v"(b));
      asm volatile("v_permlane32_swap_b32 %0, %1" : "+v"(a2), "+v"(b2));
      int4 st = {(int)a, (int)a2, (int)b, (int)b2};
      *(int4*)&outp[(n * 32 + g * 16 + hi * 8) >> 1] = st;
    }
  }
}

__global__ __launch_bounds__(256) void attn_kernel(
    const __bf16* __restrict__ Q, const __bf16* __restrict__ K,
    const __bf16* __restrict__ Vt, __bf16* __restrict__ vals) {
  __shared__ __bf16 Ks[2][4096];
  __shared__ __bf16 Vs[2][4096];  // V^T tile: [d=64][kv=64]
  const int tid = threadIdx.x;
  const int wave = tid >> 6, lane = tid & 63;
  const int lq = lane & 31, hi = lane >> 5;

  // XCD-chunked + heavy-first (LPT) dispatch:
  // XCD x gets bh in [8x,8x+8) x all 16 chunks; chunk 15 (32 tiles) first.
  const int wg = blockIdx.x + (blockIdx.y << 3);  // grid (8, 128) -> 0..1023
  const int wgid = (wg & 7) * 128 + (wg >> 3);    // bijective (1024 % 8 == 0)
  const int local = wgid & 127;
  const int bh = (wgid >> 7) * 8 + (local & 7);
  const int qc = 15 - (local >> 3);               // chunk 15 dispatched first
  const int q0w = qc * 128 + wave * 32;
  const int nt = 2 * qc + 2;

  bf16x8 qf[4];
  {
    const __bf16* qp = Q + ((size_t)bh * 2048 + q0w + lq) * 64 + hi * 8;
#pragma unroll
    for (int ds = 0; ds < 4; ++ds) qf[ds] = *(const bf16x8*)(qp + ds * 16);
  }

  f32x16 o0, o1;
#pragma unroll
  for (int i = 0; i < 16; ++i) { o0[i] = 0.f; o1[i] = 0.f; }
  float m = -3e38f, l = 0.f;

  // staging: 256 threads x 4 x 16B per tile; swizzle f(r)=(r&7)^((r>>3&3)<<1)
  // (invariant under r+=32, so rows sr and sr+32 share the source column)
  const int sr = tid >> 3, sb_ = tid & 7;
  const int sc = (sb_ ^ ((sr & 7) ^ ((sr >> 3) << 1))) * 8;
  const __bf16* Kg0 = K + ((size_t)bh * 2048 + sr) * 64 + sc;
  const __bf16* Kg1 = Kg0 + 32 * 64;
  const __bf16* Vg0 = Vt + ((size_t)bh * 64 + sr) * 2048 + sc;
  const __bf16* Vg1 = Vg0 + 32 * 2048;
  __bf16* KsW = &Ks[0][0] + wave * 512;  // wave-uniform LDS bases
  __bf16* VsW = &Vs[0][0] + wave * 512;

#define STAGE(buf, t)                                                   \
  gload_lds16(Kg0 + (size_t)(t) * 4096, KsW + (buf) * 4096);            \
  gload_lds16(Kg1 + (size_t)(t) * 4096, KsW + (buf) * 4096 + 2048);     \
  gload_lds16(Vg0 + (t) * 64, VsW + (buf) * 4096);                      \
  gload_lds16(Vg1 + (t) * 64, VsW + (buf) * 4096 + 2048);

  STAGE(0, 0);
  __syncthreads();

  for (int t = 0; t < nt; ++t) {
    const int cur = t & 1;
    if (t + 1 < nt) { STAGE(cur ^ 1, t + 1); }
    attn_tile(&Ks[cur][0], &Vs[cur][0], qf, t * 64, q0w, lq, hi, o0, o1, m, l);
    __syncthreads();
  }
#undef STAGE

  attn_epilogue(vals, bh, q0w, lq, hi, o0, o1, l);
}

// ---------------------------------------------------------------- launch
extern "C" void kernel_launch(void* const* d_in, const int* in_sizes, int n_in,
                              void* d_out, int out_size, void* d_ws, size_t ws_size,
                              hipStream_t stream) {
  const float* x = (const float*)d_in[0];
  const float* Wqkv = (const float*)d_in[1];
  const float* bqkv = (const float*)d_in[2];
  const float* Wo = (const float*)d_in[3];
  const float* bo = (const float*)d_in[4];
  float* out = (float*)d_out;
  char* ws = (char*)d_ws;

  // workspace layout (bytes)
  __bf16* xb  = (__bf16*)(ws);                 // 16 MB (x bf16; reused as vals)
  __bf16* Wqt = (__bf16*)(ws + 16777216);      // 6 MB  (W_qkv^T bf16 [3072][1024])
  __bf16* Wot = (__bf16*)(ws + 23068672);      // 2 MB  (W_o^T bf16 [1024][1024])
  __bf16* Qb  = (__bf16*)(ws + 25165824);      // 16 MB ([BH, S, 64], pre-scaled)
  __bf16* Kb  = (__bf16*)(ws + 41943040);      // 16 MB ([BH, S, 64])
  __bf16* Vtb = (__bf16*)(ws + 58720256);      // 16 MB ([BH, 64, S])
  __bf16* vals = xb;                           // attention output (scrambled matrix)

  cvt_bf16_kernel<<<4096, 256, 0, stream>>>(x, xb, 1048576);
  cvt_T_kernel<<<dim3(96, 32), 256, 0, stream>>>(Wqkv, Wqt, 1024, 3072);
  cvt_T_kernel<<<dim3(32, 32), 256, 0, stream>>>(Wo, Wot, 1024, 1024);
  gemm_bt<0, 24, 1536><<<dim3(24, 64), 256, 0, stream>>>(xb, Wqt, bqkv, Qb, Kb, Vtb, nullptr);
  attn_kernel<<<dim3(8, 128), 256, 0, stream>>>(Qb, Kb, Vtb, vals);
  gemm_bt<1, 8, 512><<<dim3(8, 64), 256, 0, stream>>>(vals, Wot, bo, nullptr, nullptr, nullptr, out);
}

// Round 6
// 171.243 us; speedup vs baseline: 1.3341x; 1.0303x over previous
//
#include <hip/hip_runtime.h>
#include <hip/hip_bf16.h>
#include <stdint.h>

// MultiHeadAttention fused forward, MI355X/gfx950.
// B=4, S=2048, H=16, hd=64, D=1024. fp32 in/out, bf16 MFMA internally.

typedef __attribute__((ext_vector_type(8))) __bf16 bf16x8;
typedef __attribute__((ext_vector_type(4))) float f32x4;
typedef __attribute__((ext_vector_type(16))) float f32x16;

#define AS_G __attribute__((address_space(1)))
#define AS_L __attribute__((address_space(3)))

__device__ __forceinline__ void gload_lds16(const void* g, void* s) {
  __builtin_amdgcn_global_load_lds((const AS_G void*)g, (AS_L void*)s, 16, 0, 0);
}

__device__ __forceinline__ unsigned cvt_pk_bf16(float lo, float hi) {
  unsigned r;
  asm("v_cvt_pk_bf16_f32 %0, %1, %2" : "=v"(r) : "v"(lo), "v"(hi));
  return r;
}

// ---------------------------------------------------------------- converts
__global__ void cvt_bf16_kernel(const float* __restrict__ in,
                                __bf16* __restrict__ out, int n8) {
  int i = blockIdx.x * blockDim.x + threadIdx.x;
  if (i >= n8) return;
  float4 a = ((const float4*)in)[i * 2];
  float4 b = ((const float4*)in)[i * 2 + 1];
  union { __bf16 h[8]; int4 v; } u;
  u.h[0] = (__bf16)a.x; u.h[1] = (__bf16)a.y; u.h[2] = (__bf16)a.z; u.h[3] = (__bf16)a.w;
  u.h[4] = (__bf16)b.x; u.h[5] = (__bf16)b.y; u.h[6] = (__bf16)b.z; u.h[7] = (__bf16)b.w;
  ((int4*)out)[i] = u.v;
}

// out[n*K + k] = (bf16) in[k*N + n]
__global__ void cvt_T_kernel(const float* __restrict__ in,
                             __bf16* __restrict__ out, int K, int N) {
  __shared__ float tile[32][33];
  int bx = blockIdx.x;  // along N
  int by = blockIdx.y;  // along K
  int tx = threadIdx.x & 31, ty = threadIdx.x >> 5;  // 32 x 8
#pragma unroll
  for (int i = 0; i < 32; i += 8)
    tile[ty + i][tx] = in[(size_t)(by * 32 + ty + i) * N + bx * 32 + tx];
  __syncthreads();
#pragma unroll
  for (int i = 0; i < 32; i += 8)
    out[(size_t)(bx * 32 + ty + i) * K + by * 32 + tx] = (__bf16)tile[tx][ty + i];
}

// ---------------------------------------------------------------- GEMM
// Counted-vmcnt 4-phase pipelined 128x128 tile, BK=64, 4 waves (2x2),
// double-buffered 64KB LDS, conflict-free XOR-swizzled layout.
// C[M,N] = A[M,1024] @ Bt[N,1024]^T  (K = 1024)
//
// Tile-walk: XCD x owns m-rows [8x, 8x+8) x ALL n-tiles, m-FASTEST within
// the chunk -> per-XCD L2 working set = 8 A-tiles (2MB, resident, reused
// NT times) + ~8 streaming B-tiles; B read once per XCD.
//
// LDS layout per buffer c: A at c*16K, B at 32K + c*16K.
//   Within: ks*8192 + v*128 + (w ^ (v&7))*16, where row r -> v=r>>1,
//   w = (r&1)*4 + u2 (u2 = 16B unit within the 32-col K-half).
// Staging writes LDS LINEARLY (global_load_lds) with inverse-swizzled
// global source (rule 21); reads apply the swizzle -> conflict-free.
// Schedule per iteration (tiles T=2i in buf0, T+1 in buf1), 4 phases:
//   ph0: compute(buf0,ks0); stage G(T+1,ks1)->buf1
//   ph1: compute(buf0,ks1); stage G(T+2,ks0)->buf0
//   ph2: compute(buf1,ks0); stage G(T+2,ks1)->buf0
//   ph3: compute(buf1,ks1); stage G(T+3,ks0)->buf1
// vmcnt(8) before every barrier (2 stage-groups always in flight, never 0).
// MODE 0: QKV projection epilogue (scatter Q*(log2e/8) / K / V^T, +bias)
// MODE 1: output projection epilogue (fp32 out, +bias)
template <int MODE, int NT, int MCHUNK>
__global__ __launch_bounds__(256, 2) void gemm_bt(
    const __bf16* __restrict__ A, const __bf16* __restrict__ Bt,
    const float* __restrict__ bias,
    __bf16* __restrict__ Qb, __bf16* __restrict__ Kb, __bf16* __restrict__ Vtb,
    float* __restrict__ Out) {
  __shared__ char lds[65536];
  const int tid = threadIdx.x;
  const int wave = tid >> 6, lane = tid & 63;
  const int lhi = lane >> 4, llo = lane & 15;
  const int wm = wave >> 1, wn = wave & 1;

  const int wg = blockIdx.x + blockIdx.y * gridDim.x;
  const int xcd = wg & 7, local = wg >> 3;  // grid size is a multiple of 8
  const int m0 = (xcd * MCHUNK + (local & (MCHUNK - 1))) * 128;
  const int n0 = (local / MCHUNK) * 128;

  // staging source precompute: line j covers linear LDS idx = j*256 + tid.
  // v = idx>>3, wl = idx&7, wg_ = wl ^ (v&7), r = 2v + (wg_>>2), u2 = wg_&3
  int S[2];
#pragma unroll
  for (int j = 0; j < 2; ++j) {
    const int idx = j * 256 + tid;
    const int v = idx >> 3, wl = idx & 7;
    const int wg_ = wl ^ (v & 7);
    const int r = (v << 1) | (wg_ >> 2), u2 = wg_ & 3;
    S[j] = r * 1024 + u2 * 8;  // element offset (row-major, stride K=1024)
  }
  const __bf16* Asrc = A + (size_t)m0 * 1024;
  const __bf16* Bsrc = Bt + (size_t)n0 * 1024;
  const int dstw = wave * 1024;  // wave-uniform LDS byte offset within line

  auto stageAB = [&](int c, int t, int ks) {
    char* ab = &lds[c * 16384 + ks * 8192];
    char* bb = &lds[32768 + c * 16384 + ks * 8192];
    const int go = t * 64 + ks * 32;
    gload_lds16(Asrc + S[0] + go, ab + dstw);
    gload_lds16(Asrc + S[1] + go, ab + 4096 + dstw);
    gload_lds16(Bsrc + S[0] + go, bb + dstw);
    gload_lds16(Bsrc + S[1] + go, bb + 4096 + dstw);
  };

  f32x4 acc[4][4];
#pragma unroll
  for (int mi = 0; mi < 4; ++mi)
#pragma unroll
    for (int nj = 0; nj < 4; ++nj) acc[mi][nj] = (f32x4){0.f, 0.f, 0.f, 0.f};

  // fragment LDS offsets (swizzled reads)
  auto aoff = [&](int c, int ks, int mi) {
    const int r = wm * 64 + mi * 16 + llo;
    const int v = r >> 1;
    const int w = ((r & 1) << 2) | lhi;
    return c * 16384 + ks * 8192 + v * 128 + ((w ^ (v & 7)) << 4);
  };
  auto boff = [&](int c, int ks, int nj) {
    const int r = wn * 64 + nj * 16 + llo;
    const int v = r >> 1;
    const int w = ((r & 1) << 2) | lhi;
    return 32768 + c * 16384 + ks * 8192 + v * 128 + ((w ^ (v & 7)) << 4);
  };

  auto phase = [&](int c, int ks, int sc, int st, int sks) {
    bf16x8 fa[4], fb[4];
#pragma unroll
    for (int mi = 0; mi < 4; ++mi) fa[mi] = *(const bf16x8*)&lds[aoff(c, ks, mi)];
#pragma unroll
    for (int nj = 0; nj < 4; ++nj) fb[nj] = *(const bf16x8*)&lds[boff(c, ks, nj)];
    stageAB(sc, st, sks);
    __builtin_amdgcn_sched_barrier(0);
    asm volatile("s_waitcnt vmcnt(8)" ::: "memory");
    __builtin_amdgcn_sched_barrier(0);
    __builtin_amdgcn_s_barrier();
    __builtin_amdgcn_s_setprio(1);
#pragma unroll
    for (int mi = 0; mi < 4; ++mi)
#pragma unroll
      for (int nj = 0; nj < 4; ++nj)
        acc[mi][nj] = __builtin_amdgcn_mfma_f32_16x16x32_bf16(fa[mi], fb[nj],
                                                              acc[mi][nj], 0, 0, 0);
    __builtin_amdgcn_s_setprio(0);
    __builtin_amdgcn_sched_barrier(0);
    __builtin_amdgcn_s_barrier();
  };

  // prologue: stage G(0,ks0), G(0,ks1), G(1,ks0); keep newest 8 in flight
  stageAB(0, 0, 0);
  stageAB(0, 0, 1);
  stageAB(1, 1, 0);
  __builtin_amdgcn_sched_barrier(0);
  asm volatile("s_waitcnt vmcnt(8)" ::: "memory");
  __builtin_amdgcn_sched_barrier(0);
  __builtin_amdgcn_s_barrier();

  for (int it = 0; it < 8; ++it) {
    const int T = 2 * it;
    phase(0, 0, 1, (T + 1) & 15, 1);
    phase(0, 1, 0, (T + 2) & 15, 0);
    phase(1, 0, 0, (T + 2) & 15, 1);
    phase(1, 1, 1, (T + 3) & 15, 0);
  }

  // ------------------------------------------------------------ epilogue
#pragma unroll
  for (int nj = 0; nj < 4; ++nj) {
    const int col = n0 + wn * 64 + nj * 16 + llo;
    const float bv = bias[col];
    if (MODE == 0) {
      const int h = col / 192, rem = col % 192;
#pragma unroll
      for (int mi = 0; mi < 4; ++mi) {
        const int row0 = m0 + wm * 64 + mi * 16 + lhi * 4;
        const int b = row0 >> 11;
        const int s0 = row0 & 2047;
        const int bh = b * 16 + h;
        f32x4 v = acc[mi][nj];
        if (rem < 64) {
          // Q pre-scaled by (1/sqrt(64)) * log2(e) for exp2-domain softmax
#pragma unroll
          for (int r = 0; r < 4; ++r)
            Qb[((size_t)bh * 2048 + s0 + r) * 64 + rem] =
                (__bf16)((v[r] + bv) * 0.18033688011112042f);
        } else if (rem < 128) {
#pragma unroll
          for (int r = 0; r < 4; ++r)
            Kb[((size_t)bh * 2048 + s0 + r) * 64 + (rem - 64)] = (__bf16)(v[r] + bv);
        } else {
          union { __bf16 h4[4]; int2 v2; } u;
#pragma unroll
          for (int r = 0; r < 4; ++r) u.h4[r] = (__bf16)(v[r] + bv);
          *(int2*)&Vtb[((size_t)bh * 64 + (rem - 128)) * 2048 + s0] = u.v2;
        }
      }
    } else {
#pragma unroll
      for (int mi = 0; mi < 4; ++mi) {
        const int row0 = m0 + wm * 64 + mi * 16 + lhi * 4;
        f32x4 v = acc[mi][nj];
#pragma unroll
        for (int r = 0; r < 4; ++r)
          Out[(size_t)(row0 + r) * 1024 + col] = v[r] + bv;
      }
    }
  }
}

// ---------------------------------------------------------------- attention
// 4 waves x 32 q-rows = 128-row chunk per block; 1024 blocks (4/CU).
// Swapped QK^T: S^T = mfma(K, Q^T)  -> lane holds S[q=lane&31][32 kv vals]
// Swapped PV:   O^T = mfma(V^T, P^T) -> lane-local rescale/normalize.
// exp2-domain softmax (Q pre-scaled by log2e/8); defer-max THR=8.

__device__ __forceinline__ void attn_tile(
    const __bf16* __restrict__ ksb, const __bf16* __restrict__ vsb,
    const bf16x8* qf, int kv0, int q0w, int lq, int hi,
    f32x16& o0, f32x16& o1, float& m, float& l) {
  const int r0 = lq, r1 = 32 + lq;
  const int fx = (lq & 7) ^ ((lq >> 3) << 1);  // matches staging swizzle
  f32x16 s0, s1;
#pragma unroll
  for (int i = 0; i < 16; ++i) { s0[i] = 0.f; s1[i] = 0.f; }
  __builtin_amdgcn_s_setprio(1);
#pragma unroll
  for (int ds = 0; ds < 4; ++ds) {
    const int bb = ((ds * 2 + hi) ^ fx) * 8;
    bf16x8 k0 = *(const bf16x8*)&ksb[r0 * 64 + bb];
    bf16x8 k1 = *(const bf16x8*)&ksb[r1 * 64 + bb];
    s0 = __builtin_amdgcn_mfma_f32_32x32x16_bf16(k0, qf[ds], s0, 0, 0, 0);
    s1 = __builtin_amdgcn_mfma_f32_32x32x16_bf16(k1, qf[ds], s1, 0, 0, 0);
  }
  __builtin_amdgcn_s_setprio(0);

  const int qg = q0w + lq;
  if (kv0 + 63 > q0w) {  // causal mask (log2 domain; -1e30 -> exp2 = 0)
#pragma unroll
    for (int reg = 0; reg < 16; ++reg) {
      const int kvl = (reg & 3) + 8 * (reg >> 2) + 4 * hi;
      if (kv0 + kvl > qg) s0[reg] = -1e30f;
      if (kv0 + 32 + kvl > qg) s1[reg] = -1e30f;
    }
  }
  // tree max over this lane's 32 scores, then combine lane-halves
  float x[8];
#pragma unroll
  for (int i = 0; i < 8; ++i)
    x[i] = fmaxf(fmaxf(s0[i], s0[i + 8]), fmaxf(s1[i], s1[i + 8]));
#pragma unroll
  for (int st = 4; st; st >>= 1)
#pragma unroll
    for (int i = 0; i < st; ++i) x[i] = fmaxf(x[i], x[i + st]);
  const float mx = fmaxf(x[0], __shfl_xor(x[0], 32));

  // defer-max: only rescale when max grew by > 8 (log2 units)
  if (!__all(mx <= m + 8.f)) {
    const float mn = fmaxf(m, mx);
    const float f = __builtin_amdgcn_exp2f(m - mn);
    m = mn;
    l *= f;
#pragma unroll
    for (int i = 0; i < 16; ++i) { o0[i] *= f; o1[i] *= f; }
  }
#pragma unroll
  for (int i = 0; i < 16; ++i) s0[i] = __builtin_amdgcn_exp2f(s0[i] - m);
#pragma unroll
  for (int i = 0; i < 16; ++i) s1[i] = __builtin_amdgcn_exp2f(s1[i] - m);
  float y[8];
#pragma unroll
  for (int i = 0; i < 8; ++i) y[i] = (s0[i] + s0[i + 8]) + (s1[i] + s1[i + 8]);
#pragma unroll
  for (int st = 4; st; st >>= 1)
#pragma unroll
    for (int i = 0; i < st; ++i) y[i] += y[i + st];
  l += y[0] + __shfl_xor(y[0], 32);

  // PV: P repack (cvt_pk + permlane32_swap) -> B-frag; V from LDS as A-frag
#pragma unroll
  for (int ks = 0; ks < 4; ++ks) {
    unsigned pa, pb, pc, pd;
    if (ks < 2) {
      pa = cvt_pk_bf16(s0[ks * 8 + 0], s0[ks * 8 + 1]);
      pb = cvt_pk_bf16(s0[ks * 8 + 2], s0[ks * 8 + 3]);
      pc = cvt_pk_bf16(s0[ks * 8 + 4], s0[ks * 8 + 5]);
      pd = cvt_pk_bf16(s0[ks * 8 + 6], s0[ks * 8 + 7]);
    } else {
      pa = cvt_pk_bf16(s1[(ks - 2) * 8 + 0], s1[(ks - 2) * 8 + 1]);
      pb = cvt_pk_bf16(s1[(ks - 2) * 8 + 2], s1[(ks - 2) * 8 + 3]);
      pc = cvt_pk_bf16(s1[(ks - 2) * 8 + 4], s1[(ks - 2) * 8 + 5]);
      pd = cvt_pk_bf16(s1[(ks - 2) * 8 + 6], s1[(ks - 2) * 8 + 7]);
    }
    asm volatile("v_permlane32_swap_b32 %0, %1" : "+v"(pa), "+v"(pc));
    asm volatile("v_permlane32_swap_b32 %0, %1" : "+v"(pb), "+v"(pd));
    union { unsigned u[4]; bf16x8 v; } pf;
    pf.u[0] = pa; pf.u[1] = pb; pf.u[2] = pc; pf.u[3] = pd;
    const int vb = ((ks * 2 + hi) ^ fx) * 8;
    bf16x8 v0 = *(const bf16x8*)&vsb[r0 * 64 + vb];
    bf16x8 v1 = *(const bf16x8*)&vsb[r1 * 64 + vb];
    o0 = __builtin_amdgcn_mfma_f32_32x32x16_bf16(v0, pf.v, o0, 0, 0, 0);
    o1 = __builtin_amdgcn_mfma_f32_32x32x16_bf16(v1, pf.v, o1, 0, 0, 0);
  }
}

__device__ __forceinline__ void attn_epilogue(
    __bf16* __restrict__ vals, int bh, int q0w, int lq, int hi,
    const f32x16& o0, const f32x16& o1, float l) {
  const float inv = 1.f / l;
  unsigned* outp = (unsigned*)(vals + ((size_t)bh * 2048 + q0w + lq) * 64);
#pragma unroll
  for (int n = 0; n < 2; ++n) {
#pragma unroll
    for (int g = 0; g < 2; ++g) {
      const float e0 = (n ? o1[g * 8 + 0] : o0[g * 8 + 0]) * inv;
      const float e1 = (n ? o1[g * 8 + 1] : o0[g * 8 + 1]) * inv;
      const float e2 = (n ? o1[g * 8 + 2] : o0[g * 8 + 2]) * inv;
      const float e3 = (n ? o1[g * 8 + 3] : o0[g * 8 + 3]) * inv;
      const float e4 = (n ? o1[g * 8 + 4] : o0[g * 8 + 4]) * inv;
      const float e5 = (n ? o1[g * 8 + 5] : o0[g * 8 + 5]) * inv;
      const float e6 = (n ? o1[g * 8 + 6] : o0[g * 8 + 6]) * inv;
      const float e7 = (n ? o1[g * 8 + 7] : o0[g * 8 + 7]) * inv;
      unsigned a = cvt_pk_bf16(e0, e1);
      unsigned a2 = cvt_pk_bf16(e2, e3);
      unsigned b = cvt_pk_bf16(e4, e5);
      unsigned b2 = cvt_pk_bf16(e6, e7);
      asm volatile("v_permlane32_swap_b32 %0, %1" : "+v"(a), "+v"(b));
      asm volatile("v_permlane32_swap_b32 %0, %1" : "+v"(a2), "+v"(b2));
      int4 st = {(int)a, (int)a2, (int)b, (int)b2};
      *(int4*)&outp[(n * 32 + g * 16 + hi * 8) >> 1] = st;
    }
  }
}

__global__ __launch_bounds__(256) void attn_kernel(
    const __bf16* __restrict__ Q, const __bf16* __restrict__ K,
    const __bf16* __restrict__ Vt, __bf16* __restrict__ vals) {
  __shared__ __bf16 Ks[2][4096];
  __shared__ __bf16 Vs[2][4096];  // V^T tile: [d=64][kv=64]
  const int tid = threadIdx.x;
  const int wave = tid >> 6, lane = tid & 63;
  const int lq = lane & 31, hi = lane >> 5;

  // XCD-chunked + heavy-first (LPT) dispatch:
  // XCD x gets bh in [8x,8x+8) x all 16 chunks; chunk 15 (32 tiles) first.
  const int wg = blockIdx.x + (blockIdx.y << 3);  // grid (8, 128) -> 0..1023
  const int wgid = (wg & 7) * 128 + (wg >> 3);    // bijective (1024 % 8 == 0)
  const int local = wgid & 127;
  const int bh = (wgid >> 7) * 8 + (local & 7);
  const int qc = 15 - (local >> 3);               // chunk 15 dispatched first
  const int q0w = qc * 128 + wave * 32;
  const int nt = 2 * qc + 2;

  bf16x8 qf[4];
  {
    const __bf16* qp = Q + ((size_t)bh * 2048 + q0w + lq) * 64 + hi * 8;
#pragma unroll
    for (int ds = 0; ds < 4; ++ds) qf[ds] = *(const bf16x8*)(qp + ds * 16);
  }

  f32x16 o0, o1;
#pragma unroll
  for (int i = 0; i < 16; ++i) { o0[i] = 0.f; o1[i] = 0.f; }
  float m = -3e38f, l = 0.f;

  // staging: 256 threads x 4 x 16B per tile; swizzle f(r)=(r&7)^((r>>3&3)<<1)
  // (invariant under r+=32, so rows sr and sr+32 share the source column)
  const int sr = tid >> 3, sb_ = tid & 7;
  const int sc = (sb_ ^ ((sr & 7) ^ ((sr >> 3) << 1))) * 8;
  const __bf16* Kg0 = K + ((size_t)bh * 2048 + sr) * 64 + sc;
  const __bf16* Kg1 = Kg0 + 32 * 64;
  const __bf16* Vg0 = Vt + ((size_t)bh * 64 + sr) * 2048 + sc;
  const __bf16* Vg1 = Vg0 + 32 * 2048;
  __bf16* KsW = &Ks[0][0] + wave * 512;  // wave-uniform LDS bases
  __bf16* VsW = &Vs[0][0] + wave * 512;

#define STAGE(buf, t)                                                   \
  gload_lds16(Kg0 + (size_t)(t) * 4096, KsW + (buf) * 4096);            \
  gload_lds16(Kg1 + (size_t)(t) * 4096, KsW + (buf) * 4096 + 2048);     \
  gload_lds16(Vg0 + (t) * 64, VsW + (buf) * 4096);                      \
  gload_lds16(Vg1 + (t) * 64, VsW + (buf) * 4096 + 2048);

  STAGE(0, 0);
  __syncthreads();

  for (int t = 0; t < nt; ++t) {
    const int cur = t & 1;
    if (t + 1 < nt) { STAGE(cur ^ 1, t + 1); }
    attn_tile(&Ks[cur][0], &Vs[cur][0], qf, t * 64, q0w, lq, hi, o0, o1, m, l);
    __syncthreads();
  }
#undef STAGE

  attn_epilogue(vals, bh, q0w, lq, hi, o0, o1, l);
}

// ---------------------------------------------------------------- launch
extern "C" void kernel_launch(void* const* d_in, const int* in_sizes, int n_in,
                              void* d_out, int out_size, void* d_ws, size_t ws_size,
                              hipStream_t stream) {
  const float* x = (const float*)d_in[0];
  const float* Wqkv = (const float*)d_in[1];
  const float* bqkv = (const float*)d_in[2];
  const float* Wo = (const float*)d_in[3];
  const float* bo = (const float*)d_in[4];
  float* out = (float*)d_out;
  char* ws = (char*)d_ws;

  // workspace layout (bytes)
  __bf16* xb  = (__bf16*)(ws);                 // 16 MB (x bf16; reused as vals)
  __bf16* Wqt = (__bf16*)(ws + 16777216);      // 6 MB  (W_qkv^T bf16 [3072][1024])
  __bf16* Wot = (__bf16*)(ws + 23068672);      // 2 MB  (W_o^T bf16 [1024][1024])
  __bf16* Qb  = (__bf16*)(ws + 25165824);      // 16 MB ([BH, S, 64], pre-scaled)
  __bf16* Kb  = (__bf16*)(ws + 41943040);      // 16 MB ([BH, S, 64])
  __bf16* Vtb = (__bf16*)(ws + 58720256);      // 16 MB ([BH, 64, S])
  __bf16* vals = xb;                           // attention output (scrambled matrix)

  cvt_bf16_kernel<<<4096, 256, 0, stream>>>(x, xb, 1048576);
  cvt_T_kernel<<<dim3(96, 32), 256, 0, stream>>>(Wqkv, Wqt, 1024, 3072);
  cvt_T_kernel<<<dim3(32, 32), 256, 0, stream>>>(Wo, Wot, 1024, 1024);
  gemm_bt<0, 24, 8><<<dim3(24, 64), 256, 0, stream>>>(xb, Wqt, bqkv, Qb, Kb, Vtb, nullptr);
  attn_kernel<<<dim3(8, 128), 256, 0, stream>>>(Qb, Kb, Vtb, vals);
  gemm_bt<1, 8, 8><<<dim3(8, 64), 256, 0, stream>>>(vals, Wot, bo, nullptr, nullptr, nullptr, out);
}